// Round 8
// baseline (354.588 us; speedup 1.0000x reference)
//
#include <hip/hip_runtime.h>
#include <hip/hip_bf16.h>
#include <stdint.h>

// S5 layer: L=16384, H=1024, P=1024. fp32 in/out. Round-8:
//   - GEMMs un-templated into two distinctly-named kernels (g1_bu, g2_out)
//     for unambiguous rocprof attribution.
//   - g1_bu reverted to round-5-exact body (NO fused aggregate epilogue:
//     r7 showed fusion cost ~15us on GEMM1 vs the 13us it saved); standalone
//     scan_phase1 restored.
//   - g2_out = round-5-exact EPI body (nontemporal fp32 store).
//   - unchanged: convert_u, prep_all, wave-parallel phase2, phase3.

#define L_SEQ 16384
#define H_DIM 1024
#define P_DIM 1024
#define NCH   256
#define TCH   64

typedef __bf16 bf16x8 __attribute__((ext_vector_type(8)));
typedef float  floatx4 __attribute__((ext_vector_type(4)));
using bf16 = __hip_bfloat16;

__device__ __forceinline__ void gld_lds16(const void* g, void* l) {
    __builtin_amdgcn_global_load_lds(
        (const __attribute__((address_space(1))) uint32_t*)g,
        (__attribute__((address_space(3))) uint32_t*)l, 16, 0, 0);
}

__device__ __forceinline__ float lo_bf(uint32_t v) { return __uint_as_float(v << 16); }
__device__ __forceinline__ float hi_bf(uint32_t v) { return __uint_as_float(v & 0xffff0000u); }
__device__ __forceinline__ uint32_t pack_bf(float r, float i) {
    bf16 rb = __float2bfloat16(r), ib = __float2bfloat16(i);
    return ((uint32_t)(*(uint16_t*)&ib) << 16) | (uint32_t)(*(uint16_t*)&rb);
}

__device__ __forceinline__ float rd(const void* p, size_t i, int f) {
    return f ? ((const float*)p)[i]
             : __bfloat162float(((const bf16*)p)[i]);
}

// per-block dtype self-detect (fp32 halfwords read as bf16 show |x|>=128)
__device__ __forceinline__ int detect_f32(const uint16_t* u) {
    __shared__ int cnt;
    if (threadIdx.x == 0) cnt = 0;
    __syncthreads();
    int c = 0;
    #pragma unroll
    for (int i = 0; i < 8; ++i) {
        int e = (u[threadIdx.x * 8 + i] >> 7) & 0xFF;
        c += (e >= 134);
    }
    if (c) atomicAdd(&cnt, c);
    __syncthreads();
    return cnt > 32;
}

// ---------------------------------------------------------------- convert u
__global__ void convert_u(const void* __restrict__ uin, bf16* __restrict__ ub) {
    const int f = detect_f32((const uint16_t*)uin);
    const size_t g = (size_t)blockIdx.x * 256 + threadIdx.x;
    if (f) {
        const float4* s = (const float4*)uin + g * 2;
        float4 a = s[0], b = s[1];
        alignas(16) bf16 t[8] = {
            __float2bfloat16(a.x), __float2bfloat16(a.y),
            __float2bfloat16(a.z), __float2bfloat16(a.w),
            __float2bfloat16(b.x), __float2bfloat16(b.y),
            __float2bfloat16(b.z), __float2bfloat16(b.w)};
        ((uint4*)ub)[g] = *(const uint4*)t;
    } else {
        ((uint4*)ub)[g] = ((const uint4*)uin)[g];
    }
}

// ---------------------------------------------------------------- prep (fused)
__global__ void prep_all(const void* __restrict__ u,
                         const void* __restrict__ Lre, const void* __restrict__ Lim,
                         const void* __restrict__ lstep, const void* __restrict__ B,
                         const void* __restrict__ C, const void* __restrict__ D,
                         bf16* __restrict__ W1t, bf16* __restrict__ W2t,
                         float* __restrict__ d_f,
                         float2* __restrict__ lam, float2* __restrict__ lamT) {
    const int f = detect_f32((const uint16_t*)u);
    const int p = blockIdx.x;
    float lr = fminf(rd(Lre, p, f), -1e-4f);
    float li = rd(Lim, p, f);
    float s  = expf(rd(lstep, p, f));
    float ea = expf(lr * s);
    float lbr = ea * cosf(li * s), lbi = ea * sinf(li * s);   // lambda_bar
    float dr = lbr - 1.0f, di = lbi;
    float den = lr * lr + li * li;
    float cr = (dr * lr + di * li) / den;                     // (lb-1)/Lambda
    float ci = (di * lr - dr * li) / den;
    if (threadIdx.x == 0) {
        lam[p] = make_float2(lbr, lbi);
        float tr = lbr, ti = lbi;                             // lambda_bar^64
        #pragma unroll
        for (int q = 0; q < 6; ++q) {
            float nr = tr * tr - ti * ti, ni = 2.0f * tr * ti;
            tr = nr; ti = ni;
        }
        lamT[p] = make_float2(tr, ti);
        d_f[p] = rd(D, p, f);
    }
    for (int h = threadIdx.x; h < H_DIM; h += blockDim.x) {
        size_t base = ((size_t)p * H_DIM + h) * 2;
        float br = rd(B, base + 0, f);
        float bi = rd(B, base + 1, f);
        W1t[(size_t)(2 * p)     * H_DIM + h] = __float2bfloat16(cr * br - ci * bi);
        W1t[(size_t)(2 * p + 1) * H_DIM + h] = __float2bfloat16(cr * bi + ci * br);
    }
    const int h = blockIdx.x;
    for (int q = threadIdx.x; q < P_DIM; q += blockDim.x) {
        size_t base = ((size_t)h * P_DIM + q) * 2;
        W2t[(size_t)h * (2 * P_DIM) + 2 * q]     = __float2bfloat16( 2.0f * rd(C, base + 0, f));
        W2t[(size_t)h * (2 * P_DIM) + 2 * q + 1] = __float2bfloat16(-2.0f * rd(C, base + 1, f));
    }
}

// ---------------------------------------------------------------- GEMM1
// Bu(L,2P) bf16 = ub(L,H) @ W1t(2P,H)^T. 128x128 tile, BK=64, XOR bank
// swizzle, XCD swizzle. Round-5-exact body.
__global__ __launch_bounds__(256) void g1_bu(
    const bf16* __restrict__ A, const bf16* __restrict__ Bt,
    bf16* __restrict__ OutBF) {
    constexpr int N = 2 * P_DIM, K = H_DIM;
    constexpr int NXB = N / 128;
    __shared__ alignas(16) uint8_t sA[128 * 128];
    __shared__ alignas(16) uint8_t sB[128 * 128];

    const int tid  = threadIdx.x;
    const int wave = tid >> 6;
    const int lane = tid & 63;
    const int bid = blockIdx.x;
    const int xr  = bid & 7;
    const int jj  = bid >> 3;
    const int bx  = jj % NXB;
    const int by  = (jj / NXB) * 8 + xr;
    const int bm  = by * 128, bn = bx * 128;
    const int wm  = (wave >> 1) * 64, wn = (wave & 1) * 64;

    floatx4 acc[4][4] = {};

    const int fr   = lane & 15;
    const int kq   = lane >> 4;
    const int srow = tid >> 3;
    const int skc  = tid & 7;

    for (int k0 = 0; k0 < K; k0 += 64) {
        #pragma unroll
        for (int q = 0; q < 4; ++q) {
            const int row = q * 32 + srow;
            const int kcg = skc ^ (row & 7);
            gld_lds16(A  + (size_t)(bm + row) * K + k0 + kcg * 8,
                      sA + q * 4096 + wave * 1024);
            gld_lds16(Bt + (size_t)(bn + row) * K + k0 + kcg * 8,
                      sB + q * 4096 + wave * 1024);
        }
        __syncthreads();
        #pragma unroll
        for (int s = 0; s < 2; ++s) {
            bf16x8 af[4], bfr[4];
            #pragma unroll
            for (int mi = 0; mi < 4; ++mi) {
                const int row = wm + mi * 16 + fr;
                const int ch  = (s * 4 + kq) ^ (row & 7);
                af[mi] = *(const bf16x8*)(sA + row * 128 + ch * 16);
            }
            #pragma unroll
            for (int ni = 0; ni < 4; ++ni) {
                const int row = wn + ni * 16 + fr;
                const int ch  = (s * 4 + kq) ^ (row & 7);
                bfr[ni] = *(const bf16x8*)(sB + row * 128 + ch * 16);
            }
            #pragma unroll
            for (int mi = 0; mi < 4; ++mi)
                #pragma unroll
                for (int ni = 0; ni < 4; ++ni)
                    acc[mi][ni] = __builtin_amdgcn_mfma_f32_16x16x32_bf16(
                        af[mi], bfr[ni], acc[mi][ni], 0, 0, 0);
        }
        __syncthreads();
    }

    const int col0  = bn + wn + fr;
    const int rbase = bm + wm + kq * 4;
    #pragma unroll
    for (int mi = 0; mi < 4; ++mi) {
        #pragma unroll
        for (int rr = 0; rr < 4; ++rr) {
            const int row = rbase + mi * 16 + rr;
            #pragma unroll
            for (int ni = 0; ni < 4; ++ni) {
                const int c = col0 + ni * 16;
                OutBF[(size_t)row * N + c] = __float2bfloat16(acc[mi][ni][rr]);
            }
        }
    }
}

// ---------------------------------------------------------------- GEMM2
// out(L,H) fp32 = X(L,2P) @ W2t(H,2P)^T + U*Dvec. Round-5-exact EPI body.
__global__ __launch_bounds__(256) void g2_out(
    const bf16* __restrict__ A, const bf16* __restrict__ Bt,
    float* __restrict__ OutF,
    const bf16* __restrict__ U, const float* __restrict__ Dvec) {
    constexpr int N = H_DIM, K = 2 * P_DIM;
    constexpr int NXB = N / 128;
    __shared__ alignas(16) uint8_t sA[128 * 128];
    __shared__ alignas(16) uint8_t sB[128 * 128];

    const int tid  = threadIdx.x;
    const int wave = tid >> 6;
    const int lane = tid & 63;
    const int bid = blockIdx.x;
    const int xr  = bid & 7;
    const int jj  = bid >> 3;
    const int bx  = jj % NXB;
    const int by  = (jj / NXB) * 8 + xr;
    const int bm  = by * 128, bn = bx * 128;
    const int wm  = (wave >> 1) * 64, wn = (wave & 1) * 64;

    floatx4 acc[4][4] = {};

    const int fr   = lane & 15;
    const int kq   = lane >> 4;
    const int srow = tid >> 3;
    const int skc  = tid & 7;

    for (int k0 = 0; k0 < K; k0 += 64) {
        #pragma unroll
        for (int q = 0; q < 4; ++q) {
            const int row = q * 32 + srow;
            const int kcg = skc ^ (row & 7);
            gld_lds16(A  + (size_t)(bm + row) * K + k0 + kcg * 8,
                      sA + q * 4096 + wave * 1024);
            gld_lds16(Bt + (size_t)(bn + row) * K + k0 + kcg * 8,
                      sB + q * 4096 + wave * 1024);
        }
        __syncthreads();
        #pragma unroll
        for (int s = 0; s < 2; ++s) {
            bf16x8 af[4], bfr[4];
            #pragma unroll
            for (int mi = 0; mi < 4; ++mi) {
                const int row = wm + mi * 16 + fr;
                const int ch  = (s * 4 + kq) ^ (row & 7);
                af[mi] = *(const bf16x8*)(sA + row * 128 + ch * 16);
            }
            #pragma unroll
            for (int ni = 0; ni < 4; ++ni) {
                const int row = wn + ni * 16 + fr;
                const int ch  = (s * 4 + kq) ^ (row & 7);
                bfr[ni] = *(const bf16x8*)(sB + row * 128 + ch * 16);
            }
            #pragma unroll
            for (int mi = 0; mi < 4; ++mi)
                #pragma unroll
                for (int ni = 0; ni < 4; ++ni)
                    acc[mi][ni] = __builtin_amdgcn_mfma_f32_16x16x32_bf16(
                        af[mi], bfr[ni], acc[mi][ni], 0, 0, 0);
        }
        __syncthreads();
    }

    const int col0  = bn + wn + fr;
    const int rbase = bm + wm + kq * 4;
    #pragma unroll
    for (int mi = 0; mi < 4; ++mi) {
        #pragma unroll
        for (int rr = 0; rr < 4; ++rr) {
            const int row = rbase + mi * 16 + rr;
            #pragma unroll
            for (int ni = 0; ni < 4; ++ni) {
                const int c = col0 + ni * 16;
                float uu = __bfloat162float(U[(size_t)row * H_DIM + c]);
                __builtin_nontemporal_store(acc[mi][ni][rr] + uu * Dvec[c],
                                            &OutF[(size_t)row * N + c]);
            }
        }
    }
}

// ---------------------------------------------------------------- scan
// Interleaved layout: row = P_DIM uint32 words; word p = (re_p | im_p<<16).
__global__ void scan_phase1(const uint32_t* __restrict__ Bu,
                            const float2* __restrict__ lam,
                            float2* __restrict__ agg) {
    const int p = blockIdx.y * 256 + threadIdx.x;
    const int c = blockIdx.x;
    const float2 lb = lam[p];
    float xr = 0.f, xi = 0.f;
    const uint32_t* b = Bu + (size_t)c * TCH * P_DIM + p;
    #pragma unroll 4
    for (int j = 0; j < TCH; ++j) {
        uint32_t v = *b;
        float nr = lb.x * xr - lb.y * xi + lo_bf(v);
        float ni = lb.x * xi + lb.y * xr + hi_bf(v);
        xr = nr; xi = ni;
        b += P_DIM;
    }
    agg[(size_t)c * P_DIM + p] = make_float2(xr, xi);
}

// phase2: wave-parallel carries. 1 wave per state; lane j owns chunks 4j..4j+3.
__global__ void scan_phase2p(const float2* __restrict__ agg,
                             const float2* __restrict__ lamT,
                             float2* __restrict__ carry) {
    const int w = threadIdx.x >> 6;
    const int j = threadIdx.x & 63;
    const int p = blockIdx.x * 4 + w;
    const float2 A = lamT[p];                               // lam^64
    float b2r = A.x * A.x - A.y * A.y, b2i = 2.f * A.x * A.y;
    float Br = b2r * b2r - b2i * b2i, Bi = 2.f * b2r * b2i; // lam^256
    float2 a[4];
    #pragma unroll
    for (int k = 0; k < 4; ++k) a[k] = agg[(size_t)(4 * j + k) * P_DIM + p];
    float xr = 0.f, xi = 0.f;
    #pragma unroll
    for (int k = 0; k < 4; ++k) {
        float nr = A.x * xr - A.y * xi + a[k].x;
        float ni = A.x * xi + A.y * xr + a[k].y;
        xr = nr; xi = ni;
    }
    float cr = Br, ci = Bi, vr = xr, vi = xi;
    #pragma unroll
    for (int d = 1; d < 64; d <<= 1) {
        float pvr = __shfl_up(vr, d), pvi = __shfl_up(vi, d);
        float pcr = __shfl_up(cr, d), pci = __shfl_up(ci, d);
        if (j >= d) {
            float nvr = cr * pvr - ci * pvi + vr;
            float nvi = cr * pvi + ci * pvr + vi;
            float ncr = cr * pcr - ci * pci;
            float nci = cr * pci + ci * pcr;
            vr = nvr; vi = nvi; cr = ncr; ci = nci;
        }
    }
    float sr = __shfl_up(vr, 1), si = __shfl_up(vi, 1);     // exclusive seed
    if (j == 0) { sr = 0.f; si = 0.f; }
    #pragma unroll
    for (int k = 0; k < 4; ++k) {
        carry[(size_t)(4 * j + k) * P_DIM + p] = make_float2(sr, si);
        float nr = A.x * sr - A.y * si + a[k].x;
        float ni = A.x * si + A.y * sr + a[k].y;
        sr = nr; si = ni;
    }
}

__global__ void scan_phase3(uint32_t* __restrict__ BuX,             // in-place
                            const float2* __restrict__ lam,
                            const float2* __restrict__ carry) {
    const int p = blockIdx.y * 256 + threadIdx.x;
    const int c = blockIdx.x;
    const float2 lb = lam[p];
    const float2 c0 = carry[(size_t)c * P_DIM + p];
    float xr = c0.x, xi = c0.y;
    uint32_t* b = BuX + (size_t)c * TCH * P_DIM + p;
    #pragma unroll 4
    for (int j = 0; j < TCH; ++j) {
        uint32_t v = *b;
        float nr = lb.x * xr - lb.y * xi + lo_bf(v);
        float ni = lb.x * xi + lb.y * xr + hi_bf(v);
        xr = nr; xi = ni;
        *b = pack_bf(xr, xi);
        b += P_DIM;
    }
}

// ---------------------------------------------------------------- launch
extern "C" void kernel_launch(void* const* d_in, const int* in_sizes, int n_in,
                              void* d_out, int out_size, void* d_ws, size_t ws_size,
                              hipStream_t stream) {
    float* out = (float*)d_out;  // (L,H) fp32

    char* w = (char*)d_ws;
    w += 256;
    float2* lam   = (float2*)w;  w += (size_t)P_DIM * 8;
    float2* lamT  = (float2*)w;  w += (size_t)P_DIM * 8;
    float*  d_f   = (float*)w;   w += (size_t)H_DIM * 4;
    float2* agg   = (float2*)w;  w += (size_t)NCH * P_DIM * 8;       // 2 MB
    float2* carry = (float2*)w;  w += (size_t)NCH * P_DIM * 8;       // 2 MB
    bf16*   W1t   = (bf16*)w;    w += (size_t)2 * P_DIM * H_DIM * 2; // 4 MB
    bf16*   W2t   = (bf16*)w;    w += (size_t)H_DIM * 2 * P_DIM * 2; // 4 MB
    bf16*   ub    = (bf16*)w;    w += (size_t)L_SEQ * H_DIM * 2;     // 33.5 MB
    bf16*   Xbuf  = (bf16*)w;                                        // 67 MB

    convert_u<<<(L_SEQ * H_DIM / 8) / 256, 256, 0, stream>>>(d_in[0], ub);
    prep_all<<<P_DIM, 256, 0, stream>>>(d_in[0], d_in[1], d_in[2], d_in[6],
                                        d_in[3], d_in[4], d_in[5],
                                        W1t, W2t, d_f, lam, lamT);

    // Bu(L,2P) = ub @ W1t^T  (interleaved cols)
    g1_bu<<<(2 * P_DIM / 128) * 128, 256, 0, stream>>>(ub, W1t, Xbuf);

    scan_phase1<<<dim3(NCH, P_DIM / 256), 256, 0, stream>>>(
        (const uint32_t*)Xbuf, lam, agg);
    scan_phase2p<<<P_DIM / 4, 256, 0, stream>>>(agg, lamT, carry);
    scan_phase3<<<dim3(NCH, P_DIM / 256), 256, 0, stream>>>(
        (uint32_t*)Xbuf, lam, carry);

    // out = X @ W2t^T + ub*D
    g2_out<<<(H_DIM / 128) * 128, 256, 0, stream>>>(Xbuf, W2t, out, ub, d_f);
}